// Round 9
// baseline (171.249 us; speedup 1.0000x reference)
//
#include <hip/hip_runtime.h>
#include <math.h>

#define B_  4
#define C1_ 256
#define C2_ 256
#define H_  64
#define W_  64
#define HW_ 4096
#define KK_ 9
#define NX_ 4194304  // B*C1*HW

// ---- Tier A (split path) ws byte offsets, total 97,142,784 ----
#define A_WA     0u           // bf16 Wa[72][4][256][8]       1,179,648
#define A_XPAIR  1179648u     // uint xpair[B][C1][HW]       16,777,216
#define A_MIDX   17956864u    // int2 midx[B][9][4096]        1,179,648
#define A_MWGT   19136512u    // float4 mwgt[B][9][4096]      2,359,296
#define A_WOM    21495808u    // bf16 Wom[72][4][32][8]         147,456
#define A_BN     21643264u    // float inv[256]; bb[256]          2,048
#define A_COLF   21645312u    // bf16 colF[256][36][4096]    75,497,472
#define A_TOTAL  97142784u

// ---- Tier B (fused fallback, R7 layout), total 13,256,704 ----
#define B_WA     0u
#define B_XBF    1179648u     // bf16 xbf[B][C1][HW]
#define B_MIDX   9568256u
#define B_MWGT   10747904u
#define B_WOM    13107200u
#define B_BN     13254656u

typedef short bf16x8 __attribute__((ext_vector_type(8)));
typedef float f32x4 __attribute__((ext_vector_type(4)));

__device__ __forceinline__ unsigned f2bfu(float f) {
  unsigned u = __builtin_bit_cast(unsigned, f);
  return (u + 0x7FFFu + ((u >> 16) & 1u)) >> 16;
}
__device__ __forceinline__ float bfl(unsigned short u) {
  return __builtin_bit_cast(float, (unsigned)u << 16);
}
__device__ __forceinline__ float bflo(unsigned g) {
  return __builtin_bit_cast(float, g << 16);
}
__device__ __forceinline__ float bfhi(unsigned g) {
  return __builtin_bit_cast(float, g & 0xFFFF0000u);
}
__device__ __forceinline__ void gload_lds16(const void* g, void* l) {
  __builtin_amdgcn_global_load_lds(
      (const __attribute__((address_space(1))) unsigned*)g,
      (__attribute__((address_space(3))) unsigned*)l, 16, 0, 0);
}

// grid 512: 8 XCDs; each XCD owns 32 consecutive rows of ONE batch.
__device__ __forceinline__ void decode_bid512(int bid, int& b, int& h, int& ph) {
  const int xcd = bid & 7, slot = bid >> 3;
  b = xcd >> 1;
  h = (xcd & 1) * 32 + (slot >> 1);
  ph = slot & 1;
}

// ---------------------------------------------------------------------------
// prep<PAIR>: xcast (2048 blks) + wt_perm (2304) + wom_perm/BN (288).
// PAIR: writes uint pairs (bf(x[i]), bf(x[i+1])); else plain bf16.
// ---------------------------------------------------------------------------
template <bool PAIR>
__global__ __launch_bounds__(256) void prep(
    const float* __restrict__ x, const float* __restrict__ w_om,
    const float* __restrict__ w_dcn, const float* __restrict__ bn_gamma,
    const float* __restrict__ bn_beta, const float* __restrict__ bn_mean,
    const float* __restrict__ bn_var, void* __restrict__ xdst,
    unsigned short* __restrict__ Wa, unsigned short* __restrict__ Wom,
    float* __restrict__ bnbuf) {
  const int bid = blockIdx.x;
  if (bid < 2048) {
    const int gid = (bid * 256 + threadIdx.x) * 8;
    const float4 v0 = *(const float4*)(x + gid);
    const float4 v1 = *(const float4*)(x + gid + 4);
    if (PAIR) {
      const float v8 = x[min(gid + 8, NX_ - 1)];
      const float vv[9] = {v0.x, v0.y, v0.z, v0.w, v1.x, v1.y, v1.z, v1.w, v8};
      unsigned o[8];
#pragma unroll
      for (int i = 0; i < 8; ++i)
        o[i] = f2bfu(vv[i]) | (f2bfu(vv[i + 1]) << 16);
      unsigned* dst = (unsigned*)xdst + gid;
      *(int4*)dst = make_int4(o[0], o[1], o[2], o[3]);
      *(int4*)(dst + 4) = make_int4(o[4], o[5], o[6], o[7]);
    } else {
      int4 o;
      o.x = f2bfu(v0.x) | (f2bfu(v0.y) << 16);
      o.y = f2bfu(v0.z) | (f2bfu(v0.w) << 16);
      o.z = f2bfu(v1.x) | (f2bfu(v1.y) << 16);
      o.w = f2bfu(v1.z) | (f2bfu(v1.w) << 16);
      *(int4*)((unsigned short*)xdst + gid) = o;
    }
  } else if (bid < 2048 + 2304) {
    const unsigned e = (bid - 2048) * 256 + threadIdx.x;  // < 589824
    const unsigned kt = e >> 13, r2 = e & 8191;
    const unsigned kg = r2 >> 11, r3 = r2 & 2047, o = r3 >> 3, j = r3 & 7;
    const unsigned ck = kt * 32 + kg * 8 + j;
    const unsigned k = ck >> 8, c = ck & 255;
    Wa[e] = (unsigned short)f2bfu(w_dcn[((size_t)o * C1_ + c) * 9 + k]);
  } else {
    const int wb = bid - (2048 + 2304);
    if (wb == 0) {
      const int o = threadIdx.x;
      float inv = bn_gamma[o] * rsqrtf(bn_var[o] + 1e-5f);
      bnbuf[o] = inv;
      bnbuf[256 + o] = bn_beta[o] - bn_mean[o] * inv;
    }
    const unsigned e = wb * 256 + threadIdx.x;  // < 73728
    const unsigned kt = e >> 10, kg = (e >> 8) & 3, o = (e >> 3) & 31, j = e & 7;
    const unsigned ck = kt * 32 + kg * 8 + j;
    const unsigned k = ck >> 8, c = ck & 255;
    const float v = (o < 27) ? w_om[((size_t)o * C1_ + c) * 9 + k] : 0.f;
    Wom[e] = (unsigned short)f2bfu(v);
  }
}

// ---------------------------------------------------------------------------
// om_gemm<PAIR>: om = Wom^T x im2col(x) via MFMA + fused meta epilogue.
// Block O=32 x P=32, 256 thr, BK=64, 36 steps; grid 512 XCD-swizzled.
// ---------------------------------------------------------------------------
template <bool PAIR>
__global__ __launch_bounds__(256) void om_gemm(
    const void* __restrict__ xsrc, const float* __restrict__ b_om,
    const unsigned short* __restrict__ Wom, int2* __restrict__ midx,
    float4* __restrict__ mwgt) {
  __shared__ short Ald[2][2048];
  __shared__ short Bld[2][2048];
  __shared__ float omld[32][33];

  int b, h, ph;
  decode_bid512(blockIdx.x, b, h, ph);
  const int tid = threadIdx.x;
  const int lane = tid & 63, wid = tid >> 6;
  const int wo = wid >> 1, wp = wid & 1;
  const int p = tid & 31;
  const int cr = tid >> 5;

  f32x4 acc = (f32x4){0.f, 0.f, 0.f, 0.f};

  auto stageA = [&](int s, int buf) {
    gload_lds16((const char*)(Wom + (size_t)s * 2048) + tid * 16,
                (char*)&Ald[buf][0] + tid * 16);
  };

  auto produce = [&](int s, int4& pk) {
    const int k = s >> 2;
    const int c0 = (s & 3) * 64 + cr * 8;
    const int hh = h - 1 + k / 3;
    const int ww = ph * 32 + p - 1 + k % 3;
    const bool v = ((unsigned)hh < (unsigned)H_) && ((unsigned)ww < (unsigned)W_);
    const int pos = v ? hh * W_ + ww : 0;
    unsigned u[8];
    if (PAIR) {
      const unsigned* pl =
          (const unsigned*)xsrc + ((size_t)b * C1_ + c0) * HW_ + pos;
#pragma unroll
      for (int i = 0; i < 8; ++i)
        u[i] = v ? (pl[(size_t)i * HW_] & 0xFFFFu) : 0u;
    } else {
      const unsigned short* pl =
          (const unsigned short*)xsrc + ((size_t)b * C1_ + c0) * HW_ + pos;
#pragma unroll
      for (int i = 0; i < 8; ++i) u[i] = v ? (unsigned)pl[(size_t)i * HW_] : 0u;
    }
    pk.x = u[0] | (u[1] << 16);
    pk.y = u[2] | (u[3] << 16);
    pk.z = u[4] | (u[5] << 16);
    pk.w = u[6] | (u[7] << 16);
  };

  const int bslot = (cr >> 2) * 1024 + (cr & 3) * 256 + p * 8;

  auto compute = [&](int buf) {
    const int kg = lane >> 4, rr = lane & 15;
#pragma unroll
    for (int kh = 0; kh < 2; ++kh) {
      bf16x8 af = *(const bf16x8*)&Ald[buf][kh * 1024 + kg * 256 + (wo * 16 + rr) * 8];
      bf16x8 bfr = *(const bf16x8*)&Bld[buf][kh * 1024 + kg * 256 + (wp * 16 + rr) * 8];
      acc = __builtin_amdgcn_mfma_f32_16x16x32_bf16(af, bfr, acc, 0, 0, 0);
    }
  };

  {
    int4 pk;
    produce(0, pk);
    *(int4*)&Bld[0][bslot] = pk;
    stageA(0, 0);
  }
  __syncthreads();

  for (int s = 0; s < 36; ++s) {
    const int cur = s & 1, nxt = cur ^ 1;
    const bool pre = (s < 35);
    int4 pk;
    if (pre) {
      produce(s + 1, pk);
      stageA(s + 1, nxt);
    }
    compute(cur);
    if (pre) *(int4*)&Bld[nxt][bslot] = pk;
    __syncthreads();
  }

  {
    const int rr = lane & 15, rh = lane >> 4;
#pragma unroll
    for (int r = 0; r < 4; ++r) omld[wo * 16 + rh * 4 + r][wp * 16 + rr] = acc[r];
  }
  __syncthreads();

  if (tid < 32) {
    const int pc = tid;
    float a[27];
#pragma unroll
    for (int oc = 0; oc < 27; ++oc) a[oc] = omld[oc][pc] + b_om[oc];

    const int pcol = ph * 32 + pc;
#pragma unroll
    for (int k = 0; k < 9; ++k) {
      float dy = fminf(fmaxf(a[2 * k], -6.f), 6.f);
      float dx = fminf(fmaxf(a[2 * k + 1], -6.f), 6.f);
      float m = 1.f / (1.f + expf(-a[18 + k]));
      float py = (float)(h - 1 + k / 3) + dy;
      float px = (float)(pcol - 1 + k % 3) + dx;
      float y0f = floorf(py), x0f = floorf(px);
      float ly = py - y0f, lx = px - x0f;
      int y0 = (int)y0f, x0 = (int)x0f;
      int y1 = y0 + 1, x1 = x0 + 1;
      const bool vy0 = ((unsigned)y0 < (unsigned)H_);
      const bool vy1 = ((unsigned)y1 < (unsigned)H_);
      const bool vx0 = ((unsigned)x0 < (unsigned)W_);
      const bool vx1 = ((unsigned)x1 < (unsigned)W_);
      int y0c = min(max(y0, 0), H_ - 1), y1c = min(max(y1, 0), H_ - 1);
      int x0c = min(max(x0, 0), W_ - 1), x1c = min(max(x1, 0), W_ - 1);
      const int xbc = min(max(x0, 0), W_ - 2);
      float wx0 = 0.f, wx1 = 0.f;
      if (vx0) { if (x0c == xbc) wx0 += 1.f - lx; else wx1 += 1.f - lx; }
      if (vx1) { if (x1c == xbc) wx0 += lx; else wx1 += lx; }
      const float wy0 = vy0 ? (1.f - ly) : 0.f;
      const float wy1 = vy1 ? ly : 0.f;
      const size_t e = ((size_t)b * KK_ + k) * HW_ + h * W_ + pcol;
      midx[e] = make_int2(y0c * W_ + xbc, y1c * W_ + xbc);
      mwgt[e] = make_float4(m * wy0 * wx0, m * wy0 * wx1, m * wy1 * wx0,
                            m * wy1 * wx1);
    }
  }
}

// ---------------------------------------------------------------------------
// im2col (tier A): barrier-free gather kernel -> colF in MFMA fragment order.
// colF[b*64+h][s][kh2][kg4][p64][j8] bf16. grid 18432 = 256 (b,h) x 72 blocks.
// Each thread: one (octet, p): 8 channels x 2 row-bases, 1 dword gather each
// (xpair packs both x-taps), writes one contiguous 16B ushort8.
// ---------------------------------------------------------------------------
__global__ __launch_bounds__(256) void im2col(
    const unsigned* __restrict__ xpair, const int2* __restrict__ midx,
    const float4* __restrict__ mwgt, short* __restrict__ colF) {
  const int bid = blockIdx.x;
  const int xcd = bid & 7;
  const int b = xcd >> 1;
  const unsigned rest = bid >> 3;          // 0..2303
  const unsigned h_lo = rest / 72u, sub = rest % 72u;
  const int h = (xcd & 1) * 32 + (int)h_lo;
  const int tid = threadIdx.x;
  const int p = tid & 63;
  const int oi = (int)sub * 4 + (tid >> 6);  // 0..287
  const int s = oi >> 3, kh = (oi >> 2) & 1, kg = oi & 3;
  const int ckb = s * 64 + kh * 32 + kg * 8;
  const int k = ckb >> 8, c0 = ckb & 255;

  const size_t em = ((size_t)b * KK_ + k) * HW_ + h * W_ + p;
  const int2 mi = midx[em];
  const float4 mw = mwgt[em];

  const unsigned* plane = xpair + ((size_t)b * C1_ + c0) * HW_;
  unsigned g0[8], g1[8];
#pragma unroll
  for (int j = 0; j < 8; ++j) {
    g0[j] = plane[mi.x];
    g1[j] = plane[mi.y];
    plane += HW_;
  }
  unsigned bf[8];
#pragma unroll
  for (int j = 0; j < 8; ++j) {
    float v = mw.x * bflo(g0[j]) + mw.y * bfhi(g0[j]) + mw.z * bflo(g1[j]) +
              mw.w * bfhi(g1[j]);
    bf[j] = f2bfu(v);
  }
  short* dst = colF + ((size_t)(b * 64 + h) * 36 + s) * 4096 +
               ((kh * 4 + kg) * 64 + p) * 8;
  *(int4*)dst = make_int4(bf[0] | (bf[1] << 16), bf[2] | (bf[3] << 16),
                          bf[4] | (bf[5] << 16), bf[6] | (bf[7] << 16));
}

// ---------------------------------------------------------------------------
// dcn_gemm (tier A): out = Wa^T x colF, fused BN+SiLU. Pure GEMM, both
// operands staged via global_load_lds. Block O=256 x P=64, 512 thr = 8 waves
// (wave 64o x 32p, 4x2 frags), BK=64, 36 steps. LDS 80 KB -> 2 blocks/CU.
// grid 256 = (b,h), XCD-swizzled.
// ---------------------------------------------------------------------------
__global__ __launch_bounds__(512, 4) void dcn_gemm(
    const unsigned short* __restrict__ Wa, const short* __restrict__ colF,
    const float* __restrict__ bnbuf, float* __restrict__ out) {
  __shared__ short Ald[2][16384];  // [kh2][kg4][o256][j8]  32 KB/buf
  __shared__ short Bld[2][4096];   // [kh2][kg4][p64][j8]    8 KB/buf

  const int bid = blockIdx.x;
  const int xcd = bid & 7;
  const int b = xcd >> 1;
  const int h = (xcd & 1) * 32 + (bid >> 3);
  const int tid = threadIdx.x;
  const int lane = tid & 63, wid = tid >> 6;
  const int wo = wid >> 1, wp = wid & 1;

  const short* colFb = colF + (size_t)(b * 64 + h) * 36 * 4096;

  f32x4 acc[4][2];
#pragma unroll
  for (int i = 0; i < 4; ++i)
#pragma unroll
    for (int j = 0; j < 2; ++j) acc[i][j] = (f32x4){0.f, 0.f, 0.f, 0.f};

  auto stage = [&](int s, int buf) {
    const char* srcA = (const char*)(Wa + (size_t)s * 16384);
#pragma unroll
    for (int r = 0; r < 4; ++r) {
      const int chunk = r * 512 + tid;
      gload_lds16(srcA + chunk * 16, (char*)&Ald[buf][0] + chunk * 16);
    }
    gload_lds16((const char*)(colFb + (size_t)s * 4096) + tid * 16,
                (char*)&Bld[buf][0] + tid * 16);
  };

  auto compute = [&](int buf) {
    const int kg = lane >> 4, rr = lane & 15;
    bf16x8 af[4][2], bfr[2][2];
#pragma unroll
    for (int kh = 0; kh < 2; ++kh) {
#pragma unroll
      for (int fm = 0; fm < 4; ++fm)
        af[fm][kh] = *(const bf16x8*)&Ald[buf][kh * 8192 + kg * 2048 +
                                              (wo * 64 + fm * 16 + rr) * 8];
#pragma unroll
      for (int fn = 0; fn < 2; ++fn)
        bfr[fn][kh] = *(const bf16x8*)&Bld[buf][kh * 2048 + kg * 512 +
                                               (wp * 32 + fn * 16 + rr) * 8];
    }
#pragma unroll
    for (int kh = 0; kh < 2; ++kh)
#pragma unroll
      for (int fm = 0; fm < 4; ++fm)
#pragma unroll
        for (int fn = 0; fn < 2; ++fn)
          acc[fm][fn] = __builtin_amdgcn_mfma_f32_16x16x32_bf16(
              af[fm][kh], bfr[fn][kh], acc[fm][fn], 0, 0, 0);
  };

  stage(0, 0);
  __syncthreads();
  for (int s = 0; s < 36; ++s) {
    const int cur = s & 1;
    if (s < 35) stage(s + 1, cur ^ 1);
    compute(cur);
    __syncthreads();
  }

  const float* bninv = bnbuf;
  const float* bnbb = bnbuf + 256;
  const int rr = lane & 15, rh = lane >> 4;
#pragma unroll
  for (int fm = 0; fm < 4; ++fm) {
#pragma unroll
    for (int r = 0; r < 4; ++r) {
      const int o = wo * 64 + fm * 16 + rh * 4 + r;
      const float inv = bninv[o], bb = bnbb[o];
#pragma unroll
      for (int fn = 0; fn < 2; ++fn) {
        float t = acc[fm][fn][r] * inv + bb;
        float sv = t / (1.f + expf(-t));
        out[(size_t)(b * C2_ + o) * HW_ + h * W_ + wp * 32 + fn * 16 + rr] = sv;
      }
    }
  }
}

// ---------------------------------------------------------------------------
// dcn_fused (tier B fallback): R7's 87.7 us kernel, pointer-arg form.
// ---------------------------------------------------------------------------
__global__ __launch_bounds__(512, 4) void dcn_fused(
    const unsigned short* __restrict__ Wa, const unsigned short* __restrict__ xbf,
    const int2* __restrict__ midxg, const float4* __restrict__ mwgtg,
    const float* __restrict__ bnbuf, float* __restrict__ out) {
  __shared__ short Ald[2][16384];
  __shared__ short Bld[2][2048];

  int b, h, ph;
  decode_bid512(blockIdx.x, b, h, ph);
  const int tid = threadIdx.x;
  const int lane = tid & 63, wid = tid >> 6;
  const int p = tid & 31;
  const int cr = tid >> 5;

  const unsigned short* xb = xbf + (size_t)b * C1_ * HW_;
  const int pg = h * W_ + ph * 32 + p;
  const int2* midx = midxg + (size_t)b * KK_ * HW_ + pg;
  const float4* mwgt = mwgtg + (size_t)b * KK_ * HW_ + pg;

  f32x4 acc[2][2];
#pragma unroll
  for (int i = 0; i < 2; ++i)
#pragma unroll
    for (int j = 0; j < 2; ++j) acc[i][j] = (f32x4){0.f, 0.f, 0.f, 0.f};

  int2 mi;
  float4 mw;

  auto stageA = [&](int s, int buf) {
    const char* src = (const char*)(Wa + (size_t)s * 16384);
#pragma unroll
    for (int r = 0; r < 4; ++r) {
      const int chunk = r * 512 + tid;
      gload_lds16(src + chunk * 16, (char*)&Ald[buf][0] + chunk * 16);
    }
  };

  auto issue = [&](int s, unsigned short (&rg)[16]) {
    const int k = s >> 2;
    if ((s & 3) == 0) {
      mi = midx[(size_t)k * HW_];
      mw = mwgt[(size_t)k * HW_];
    }
    const unsigned short* base = xb + (size_t)((s & 3) * 64 + cr * 4) * HW_;
#pragma unroll
    for (int i = 0; i < 4; ++i) {
      rg[4 * i + 0] = base[mi.x];
      rg[4 * i + 1] = base[mi.x + 1];
      rg[4 * i + 2] = base[mi.y];
      rg[4 * i + 3] = base[mi.y + 1];
      base += HW_;
    }
  };

  auto pack = [&](const unsigned short (&rg)[16], int2& pk) {
    unsigned bf[4];
#pragma unroll
    for (int i = 0; i < 4; ++i) {
      float v = mw.x * bfl(rg[4 * i]) + mw.y * bfl(rg[4 * i + 1]) +
                mw.z * bfl(rg[4 * i + 2]) + mw.w * bfl(rg[4 * i + 3]);
      bf[i] = f2bfu(v);
    }
    pk.x = bf[0] | (bf[1] << 16);
    pk.y = bf[2] | (bf[3] << 16);
  };

  const int bslot = (cr >> 3) * 1024 + ((cr >> 1) & 3) * 256 + p * 8 + (cr & 1) * 4;

  auto compute = [&](int buf) {
    const int kg = lane >> 4, rr = lane & 15;
    bf16x8 af[2][2], bfr[2][2];
#pragma unroll
    for (int kh = 0; kh < 2; ++kh) {
#pragma unroll
      for (int fm = 0; fm < 2; ++fm)
        af[fm][kh] = *(const bf16x8*)&Ald[buf][kh * 8192 + kg * 2048 +
                                              (wid * 32 + fm * 16 + rr) * 8];
#pragma unroll
      for (int fn = 0; fn < 2; ++fn)
        bfr[fn][kh] =
            *(const bf16x8*)&Bld[buf][kh * 1024 + kg * 256 + (fn * 16 + rr) * 8];
    }
#pragma unroll
    for (int kh = 0; kh < 2; ++kh)
#pragma unroll
      for (int fm = 0; fm < 2; ++fm)
#pragma unroll
        for (int fn = 0; fn < 2; ++fn)
          acc[fm][fn] = __builtin_amdgcn_mfma_f32_16x16x32_bf16(
              af[fm][kh], bfr[fn][kh], acc[fm][fn], 0, 0, 0);
  };

  unsigned short rg[16];
  {
    int2 pk;
    issue(0, rg);
    pack(rg, pk);
    *(int2*)&Bld[0][bslot] = pk;
    stageA(0, 0);
  }
  __syncthreads();

  for (int s = 0; s < 36; ++s) {
    const int cur = s & 1, nxt = cur ^ 1;
    const bool pre = (s < 35);
    if (pre) {
      issue(s + 1, rg);
      stageA(s + 1, nxt);
    }
    compute(cur);
    if (pre) {
      int2 pk;
      pack(rg, pk);
      *(int2*)&Bld[nxt][bslot] = pk;
    }
    __syncthreads();
  }

  const float* bninv = bnbuf;
  const float* bnbb = bnbuf + 256;
  const int rr = lane & 15, rh = lane >> 4;
#pragma unroll
  for (int fm = 0; fm < 2; ++fm) {
#pragma unroll
    for (int r = 0; r < 4; ++r) {
      const int o = wid * 32 + fm * 16 + rh * 4 + r;
      const float inv = bninv[o], bb = bnbb[o];
#pragma unroll
      for (int fn = 0; fn < 2; ++fn) {
        float t = acc[fm][fn][r] * inv + bb;
        float sv = t / (1.f + expf(-t));
        out[(size_t)(b * C2_ + o) * HW_ + h * W_ + ph * 32 + fn * 16 + rr] = sv;
      }
    }
  }
}

// ---------------------------------------------------------------------------
extern "C" void kernel_launch(void* const* d_in, const int* in_sizes, int n_in,
                              void* d_out, int out_size, void* d_ws,
                              size_t ws_size, hipStream_t stream) {
  const float* x = (const float*)d_in[0];
  const float* w_om = (const float*)d_in[1];
  const float* b_om = (const float*)d_in[2];
  const float* w_dcn = (const float*)d_in[3];
  const float* bn_gamma = (const float*)d_in[4];
  const float* bn_beta = (const float*)d_in[5];
  const float* bn_mean = (const float*)d_in[6];
  const float* bn_var = (const float*)d_in[7];
  float* out = (float*)d_out;
  char* wsb = (char*)d_ws;

  if (ws_size >= (size_t)A_TOTAL) {
    // ---- Tier A: split im2col + GEMM ----
    unsigned short* Wa = (unsigned short*)(wsb + A_WA);
    unsigned* xpair = (unsigned*)(wsb + A_XPAIR);
    int2* midx = (int2*)(wsb + A_MIDX);
    float4* mwgt = (float4*)(wsb + A_MWGT);
    unsigned short* Wom = (unsigned short*)(wsb + A_WOM);
    float* bnbuf = (float*)(wsb + A_BN);
    short* colF = (short*)(wsb + A_COLF);

    prep<true><<<2048 + 2304 + 288, 256, 0, stream>>>(
        x, w_om, w_dcn, bn_gamma, bn_beta, bn_mean, bn_var, (void*)xpair, Wa,
        Wom, bnbuf);
    om_gemm<true><<<512, 256, 0, stream>>>((const void*)xpair, b_om, Wom, midx,
                                           mwgt);
    im2col<<<18432, 256, 0, stream>>>(xpair, midx, mwgt, colF);
    dcn_gemm<<<256, 512, 0, stream>>>(Wa, colF, bnbuf, out);
  } else {
    // ---- Tier B: R7 fused fallback ----
    unsigned short* Wa = (unsigned short*)(wsb + B_WA);
    unsigned short* xbf = (unsigned short*)(wsb + B_XBF);
    int2* midx = (int2*)(wsb + B_MIDX);
    float4* mwgt = (float4*)(wsb + B_MWGT);
    unsigned short* Wom = (unsigned short*)(wsb + B_WOM);
    float* bnbuf = (float*)(wsb + B_BN);

    prep<false><<<2048 + 2304 + 288, 256, 0, stream>>>(
        x, w_om, w_dcn, bn_gamma, bn_beta, bn_mean, bn_var, (void*)xbf, Wa, Wom,
        bnbuf);
    om_gemm<false><<<512, 256, 0, stream>>>((const void*)xbf, b_om, Wom, midx,
                                            mwgt);
    dcn_fused<<<512, 512, 0, stream>>>(Wa, xbf, midx, mwgt, bnbuf, out);
  }
}

// Round 10
// 144.944 us; speedup vs baseline: 1.1815x; 1.1815x over previous
//
#include <hip/hip_runtime.h>
#include <math.h>

#define B_  4
#define C1_ 256
#define C2_ 256
#define H_  64
#define W_  64
#define HW_ 4096
#define KK_ 9

// ws byte offsets (total 88,754,176 — proven ws >= 97,142,784 in R9)
#define A_WA     0u           // bf16 Wa[72][4][256][8]       1,179,648
#define A_XBF    1179648u     // bf16 xbf[B][C1][HW]          8,388,608
#define A_MIDX   9568256u     // int2 midx[B][9][4096]        1,179,648
#define A_MWGT   10747904u    // float4 mwgt[B][9][4096]      2,359,296
#define A_WOM    13107200u    // bf16 Wom[72][4][32][8]         147,456
#define A_BN     13254656u    // float inv[256]; bb[256]          2,048
#define A_COLF   13256704u    // bf16 colF[256][36][4096]    75,497,472

typedef short bf16x8 __attribute__((ext_vector_type(8)));
typedef float f32x4 __attribute__((ext_vector_type(4)));

__device__ __forceinline__ unsigned f2bfu(float f) {
  unsigned u = __builtin_bit_cast(unsigned, f);
  return (u + 0x7FFFu + ((u >> 16) & 1u)) >> 16;
}
__device__ __forceinline__ float bfl(unsigned short u) {
  return __builtin_bit_cast(float, (unsigned)u << 16);
}
__device__ __forceinline__ void gload_lds16(const void* g, void* l) {
  __builtin_amdgcn_global_load_lds(
      (const __attribute__((address_space(1))) unsigned*)g,
      (__attribute__((address_space(3))) unsigned*)l, 16, 0, 0);
}

// grid 512: 8 XCDs; each XCD owns 32 consecutive rows of ONE batch.
__device__ __forceinline__ void decode_bid512(int bid, int& b, int& h, int& ph) {
  const int xcd = bid & 7, slot = bid >> 3;
  b = xcd >> 1;
  h = (xcd & 1) * 32 + (slot >> 1);
  ph = slot & 1;
}

// ---------------------------------------------------------------------------
// prep: xcast (2048 blks) + wt_perm (2304) + wom_perm/BN (288).
// ---------------------------------------------------------------------------
__global__ __launch_bounds__(256) void prep(
    const float* __restrict__ x, const float* __restrict__ w_om,
    const float* __restrict__ w_dcn, const float* __restrict__ bn_gamma,
    const float* __restrict__ bn_beta, const float* __restrict__ bn_mean,
    const float* __restrict__ bn_var, unsigned short* __restrict__ xbf,
    unsigned short* __restrict__ Wa, unsigned short* __restrict__ Wom,
    float* __restrict__ bnbuf) {
  const int bid = blockIdx.x;
  if (bid < 2048) {
    const int gid = (bid * 256 + threadIdx.x) * 8;
    const float4 v0 = *(const float4*)(x + gid);
    const float4 v1 = *(const float4*)(x + gid + 4);
    int4 o;
    o.x = f2bfu(v0.x) | (f2bfu(v0.y) << 16);
    o.y = f2bfu(v0.z) | (f2bfu(v0.w) << 16);
    o.z = f2bfu(v1.x) | (f2bfu(v1.y) << 16);
    o.w = f2bfu(v1.z) | (f2bfu(v1.w) << 16);
    *(int4*)(xbf + gid) = o;
  } else if (bid < 2048 + 2304) {
    const unsigned e = (bid - 2048) * 256 + threadIdx.x;  // < 589824
    const unsigned kt = e >> 13, r2 = e & 8191;
    const unsigned kg = r2 >> 11, r3 = r2 & 2047, o = r3 >> 3, j = r3 & 7;
    const unsigned ck = kt * 32 + kg * 8 + j;
    const unsigned k = ck >> 8, c = ck & 255;
    Wa[e] = (unsigned short)f2bfu(w_dcn[((size_t)o * C1_ + c) * 9 + k]);
  } else {
    const int wb = bid - (2048 + 2304);
    if (wb == 0) {
      const int o = threadIdx.x;
      float inv = bn_gamma[o] * rsqrtf(bn_var[o] + 1e-5f);
      bnbuf[o] = inv;
      bnbuf[256 + o] = bn_beta[o] - bn_mean[o] * inv;
    }
    const unsigned e = wb * 256 + threadIdx.x;  // < 73728
    const unsigned kt = e >> 10, kg = (e >> 8) & 3, o = (e >> 3) & 31, j = e & 7;
    const unsigned ck = kt * 32 + kg * 8 + j;
    const unsigned k = ck >> 8, c = ck & 255;
    const float v = (o < 27) ? w_om[((size_t)o * C1_ + c) * 9 + k] : 0.f;
    Wom[e] = (unsigned short)f2bfu(v);
  }
}

// ---------------------------------------------------------------------------
// om_gemm: om = Wom^T x im2col(xbf) via MFMA + fused meta epilogue.
// Block O=32 x P=32, 256 thr, BK=128 -> 18 steps (half the barriers of R7).
// grid 512 (2 blocks/CU), XCD-swizzled.
// ---------------------------------------------------------------------------
__global__ __launch_bounds__(256) void om_gemm(
    const unsigned short* __restrict__ xbf, const float* __restrict__ b_om,
    const unsigned short* __restrict__ Wom, int2* __restrict__ midx,
    float4* __restrict__ mwgt) {
  __shared__ short Ald[2][4096];  // [16 kg][32 o][8 j]
  __shared__ short Bld[2][4096];  // [16 kg][32 p][8 j]
  __shared__ float omld[32][33];

  int b, h, ph;
  decode_bid512(blockIdx.x, b, h, ph);
  const int tid = threadIdx.x;
  const int lane = tid & 63, wid = tid >> 6;
  const int wo = wid >> 1, wp = wid & 1;
  const int p = tid & 31;
  const int cr = tid >> 5;  // 8 groups x 16 channels

  const unsigned short* xb = xbf + (size_t)b * C1_ * HW_;

  f32x4 acc = (f32x4){0.f, 0.f, 0.f, 0.f};

  auto stageA = [&](int s, int buf) {
    const char* src = (const char*)(Wom + (size_t)s * 4096);
    gload_lds16(src + tid * 16, (char*)&Ald[buf][0] + tid * 16);
    gload_lds16(src + (256 + tid) * 16, (char*)&Ald[buf][0] + (256 + tid) * 16);
  };

  // step s: k = s>>1, channel half = (s&1)*128; thread loads 16 channels
  auto produce = [&](int s, unsigned (&u)[16]) {
    const int k = s >> 1;
    const int c0 = (s & 1) * 128 + cr * 16;
    const int hh = h - 1 + k / 3;
    const int ww = ph * 32 + p - 1 + k % 3;
    const bool v = ((unsigned)hh < (unsigned)H_) && ((unsigned)ww < (unsigned)W_);
    const unsigned short* pl = xb + (size_t)c0 * HW_ + (v ? hh * W_ + ww : 0);
#pragma unroll
    for (int i = 0; i < 16; ++i) u[i] = v ? (unsigned)pl[(size_t)i * HW_] : 0u;
  };

  const int bslot = (cr * 2) * 256 + p * 8;  // shorts; second half +256

  auto bwrite = [&](const unsigned (&u)[16], int buf) {
    *(int4*)&Bld[buf][bslot] =
        make_int4(u[0] | (u[1] << 16), u[2] | (u[3] << 16), u[4] | (u[5] << 16),
                  u[6] | (u[7] << 16));
    *(int4*)&Bld[buf][bslot + 256] =
        make_int4(u[8] | (u[9] << 16), u[10] | (u[11] << 16),
                  u[12] | (u[13] << 16), u[14] | (u[15] << 16));
  };

  auto compute = [&](int buf) {
    const int kg = lane >> 4, rr = lane & 15;
#pragma unroll
    for (int kh = 0; kh < 4; ++kh) {
      bf16x8 af = *(const bf16x8*)&Ald[buf][(kh * 4 + kg) * 256 + (wo * 16 + rr) * 8];
      bf16x8 bfr = *(const bf16x8*)&Bld[buf][(kh * 4 + kg) * 256 + (wp * 16 + rr) * 8];
      acc = __builtin_amdgcn_mfma_f32_16x16x32_bf16(af, bfr, acc, 0, 0, 0);
    }
  };

  {
    unsigned u[16];
    produce(0, u);
    bwrite(u, 0);
    stageA(0, 0);
  }
  __syncthreads();

  for (int s = 0; s < 18; ++s) {
    const int cur = s & 1, nxt = cur ^ 1;
    const bool pre = (s < 17);
    unsigned u[16];
    if (pre) {
      produce(s + 1, u);   // loads in flight during compute
      stageA(s + 1, nxt);
    }
    compute(cur);
    if (pre) bwrite(u, nxt);
    __syncthreads();
  }

  {
    const int rr = lane & 15, rh = lane >> 4;
#pragma unroll
    for (int r = 0; r < 4; ++r) omld[wo * 16 + rh * 4 + r][wp * 16 + rr] = acc[r];
  }
  __syncthreads();

  if (tid < 32) {
    const int pc = tid;
    float a[27];
#pragma unroll
    for (int oc = 0; oc < 27; ++oc) a[oc] = omld[oc][pc] + b_om[oc];

    const int pcol = ph * 32 + pc;
#pragma unroll
    for (int k = 0; k < 9; ++k) {
      float dy = fminf(fmaxf(a[2 * k], -6.f), 6.f);
      float dx = fminf(fmaxf(a[2 * k + 1], -6.f), 6.f);
      float m = 1.f / (1.f + expf(-a[18 + k]));
      float py = (float)(h - 1 + k / 3) + dy;
      float px = (float)(pcol - 1 + k % 3) + dx;
      float y0f = floorf(py), x0f = floorf(px);
      float ly = py - y0f, lx = px - x0f;
      int y0 = (int)y0f, x0 = (int)x0f;
      int y1 = y0 + 1, x1 = x0 + 1;
      const bool vy0 = ((unsigned)y0 < (unsigned)H_);
      const bool vy1 = ((unsigned)y1 < (unsigned)H_);
      const bool vx0 = ((unsigned)x0 < (unsigned)W_);
      const bool vx1 = ((unsigned)x1 < (unsigned)W_);
      int y0c = min(max(y0, 0), H_ - 1), y1c = min(max(y1, 0), H_ - 1);
      int x0c = min(max(x0, 0), W_ - 1), x1c = min(max(x1, 0), W_ - 1);
      const int xbc = min(max(x0, 0), W_ - 2);
      float wx0 = 0.f, wx1 = 0.f;
      if (vx0) { if (x0c == xbc) wx0 += 1.f - lx; else wx1 += 1.f - lx; }
      if (vx1) { if (x1c == xbc) wx0 += lx; else wx1 += lx; }
      const float wy0 = vy0 ? (1.f - ly) : 0.f;
      const float wy1 = vy1 ? ly : 0.f;
      const size_t e = ((size_t)b * KK_ + k) * HW_ + h * W_ + pcol;
      midx[e] = make_int2(y0c * W_ + xbc, y1c * W_ + xbc);
      mwgt[e] = make_float4(m * wy0 * wx0, m * wy0 * wx1, m * wy1 * wx0,
                            m * wy1 * wx1);
    }
  }
}

// ---------------------------------------------------------------------------
// im2col: barrier-free gather -> colF in MFMA fragment order.
// colF[(b*64+h)][s36][kh2][kg4][p64][j8] bf16. grid 18432 = 256 (b,h) x 72.
// Each thread: 8 channels x 2 row-bases x 2 taps (32 ushort loads), one
// contiguous 16B write.
// ---------------------------------------------------------------------------
__global__ __launch_bounds__(256) void im2col(
    const unsigned short* __restrict__ xbf, const int2* __restrict__ midx,
    const float4* __restrict__ mwgt, short* __restrict__ colF) {
  const int bid = blockIdx.x;
  const int xcd = bid & 7;
  const int b = xcd >> 1;
  const unsigned rest = bid >> 3;          // 0..2303
  const unsigned h_lo = rest / 72u, sub = rest % 72u;
  const int h = (xcd & 1) * 32 + (int)h_lo;
  const int tid = threadIdx.x;
  const int p = tid & 63;
  const int oi = (int)sub * 4 + (tid >> 6);  // 0..287
  const int s = oi >> 3, kh = (oi >> 2) & 1, kg = oi & 3;
  const int ckb = s * 64 + kh * 32 + kg * 8;
  const int k = ckb >> 8, c0 = ckb & 255;

  const size_t em = ((size_t)b * KK_ + k) * HW_ + h * W_ + p;
  const int2 mi = midx[em];
  const float4 mw = mwgt[em];

  const unsigned short* plane = xbf + ((size_t)b * C1_ + c0) * HW_;
  unsigned short g0a[8], g0b[8], g1a[8], g1b[8];
#pragma unroll
  for (int j = 0; j < 8; ++j) {
    g0a[j] = plane[mi.x];
    g0b[j] = plane[mi.x + 1];
    g1a[j] = plane[mi.y];
    g1b[j] = plane[mi.y + 1];
    plane += HW_;
  }
  unsigned bf[8];
#pragma unroll
  for (int j = 0; j < 8; ++j) {
    float v = mw.x * bfl(g0a[j]) + mw.y * bfl(g0b[j]) + mw.z * bfl(g1a[j]) +
              mw.w * bfl(g1b[j]);
    bf[j] = f2bfu(v);
  }
  short* dst = colF + ((size_t)(b * 64 + h) * 36 + s) * 4096 +
               ((kh * 4 + kg) * 64 + p) * 8;
  *(int4*)dst = make_int4(bf[0] | (bf[1] << 16), bf[2] | (bf[3] << 16),
                          bf[4] | (bf[5] << 16), bf[6] | (bf[7] << 16));
}

// ---------------------------------------------------------------------------
// dcn_gemm: out = Wa^T x colF, fused BN+SiLU. Pure GEMM, both operands via
// global_load_lds. Block O=128 x P=64, 256 thr = 4 waves (wave 64o x 32p,
// 4x2 frags), BK=64, 36 steps. LDS 48 KB -> grid 512 = 2 blocks/CU so the
// per-step barrier drain overlaps with the co-resident block.
// ---------------------------------------------------------------------------
__global__ __launch_bounds__(256) void dcn_gemm(
    const unsigned short* __restrict__ Wa, const short* __restrict__ colF,
    const float* __restrict__ bnbuf, float* __restrict__ out) {
  __shared__ short Ald[2][8192];  // [2 kt'][4 kg][128 o][8 j]  16 KB/buf
  __shared__ short Bld[2][4096];  // [2 kh][4 kg][64 p][8 j]     8 KB/buf

  const int bid = blockIdx.x;
  const int xcd = bid & 7;
  const int b = xcd >> 1;
  const int rest = bid >> 3;  // 0..63
  const int oh = rest & 1;
  const int h = (xcd & 1) * 32 + (rest >> 1);
  const int tid = threadIdx.x;
  const int lane = tid & 63, wid = tid >> 6;
  const int wo = wid >> 1, wp = wid & 1;

  const short* colFb = colF + (size_t)(b * 64 + h) * 36 * 4096;

  f32x4 acc[4][2];
#pragma unroll
  for (int i = 0; i < 4; ++i)
#pragma unroll
    for (int j = 0; j < 2; ++j) acc[i][j] = (f32x4){0.f, 0.f, 0.f, 0.f};

  auto stage = [&](int s, int buf) {
    // A: rows o = oh*128 .. +128 of Wa step slabs 2s, 2s+1
#pragma unroll
    for (int r = 0; r < 4; ++r) {
      const int c = r * 256 + tid;           // 0..1023
      const int slice = c >> 7;              // kt'*4+kg
      const int wtn = c & 127;               // o within 128
      const size_t srcs = (size_t)(2 * s + (slice >> 2)) * 8192 +
                          (size_t)(slice & 3) * 2048 + (size_t)oh * 1024 +
                          (size_t)wtn * 8;
      gload_lds16((const char*)(Wa + srcs), (char*)&Ald[buf][0] + c * 16);
    }
#pragma unroll
    for (int r = 0; r < 2; ++r) {
      const int c = r * 256 + tid;
      gload_lds16((const char*)(colFb + (size_t)s * 4096) + c * 16,
                  (char*)&Bld[buf][0] + c * 16);
    }
  };

  auto compute = [&](int buf) {
    const int kg = lane >> 4, rr = lane & 15;
    bf16x8 af[4][2], bfr[2][2];
#pragma unroll
    for (int kh = 0; kh < 2; ++kh) {
#pragma unroll
      for (int fm = 0; fm < 4; ++fm)
        af[fm][kh] = *(const bf16x8*)&Ald[buf][kh * 4096 + kg * 1024 +
                                              (wo * 64 + fm * 16 + rr) * 8];
#pragma unroll
      for (int fn = 0; fn < 2; ++fn)
        bfr[fn][kh] = *(const bf16x8*)&Bld[buf][kh * 2048 + kg * 512 +
                                               (wp * 32 + fn * 16 + rr) * 8];
    }
#pragma unroll
    for (int kh = 0; kh < 2; ++kh)
#pragma unroll
      for (int fm = 0; fm < 4; ++fm)
#pragma unroll
        for (int fn = 0; fn < 2; ++fn)
          acc[fm][fn] = __builtin_amdgcn_mfma_f32_16x16x32_bf16(
              af[fm][kh], bfr[fn][kh], acc[fm][fn], 0, 0, 0);
  };

  stage(0, 0);
  __syncthreads();
  for (int s = 0; s < 36; ++s) {
    const int cur = s & 1;
    if (s < 35) stage(s + 1, cur ^ 1);
    compute(cur);
    __syncthreads();
  }

  const float* bninv = bnbuf;
  const float* bnbb = bnbuf + 256;
  const int rr = lane & 15, rh = lane >> 4;
#pragma unroll
  for (int fm = 0; fm < 4; ++fm) {
#pragma unroll
    for (int r = 0; r < 4; ++r) {
      const int o = oh * 128 + wo * 64 + fm * 16 + rh * 4 + r;
      const float inv = bninv[o], bb = bnbb[o];
#pragma unroll
      for (int fn = 0; fn < 2; ++fn) {
        float t = acc[fm][fn][r] * inv + bb;
        float sv = t / (1.f + expf(-t));
        out[(size_t)(b * C2_ + o) * HW_ + h * W_ + wp * 32 + fn * 16 + rr] = sv;
      }
    }
  }
}

// ---------------------------------------------------------------------------
extern "C" void kernel_launch(void* const* d_in, const int* in_sizes, int n_in,
                              void* d_out, int out_size, void* d_ws,
                              size_t ws_size, hipStream_t stream) {
  const float* x = (const float*)d_in[0];
  const float* w_om = (const float*)d_in[1];
  const float* b_om = (const float*)d_in[2];
  const float* w_dcn = (const float*)d_in[3];
  const float* bn_gamma = (const float*)d_in[4];
  const float* bn_beta = (const float*)d_in[5];
  const float* bn_mean = (const float*)d_in[6];
  const float* bn_var = (const float*)d_in[7];
  float* out = (float*)d_out;
  char* wsb = (char*)d_ws;

  unsigned short* Wa = (unsigned short*)(wsb + A_WA);
  unsigned short* xbf = (unsigned short*)(wsb + A_XBF);
  int2* midx = (int2*)(wsb + A_MIDX);
  float4* mwgt = (float4*)(wsb + A_MWGT);
  unsigned short* Wom = (unsigned short*)(wsb + A_WOM);
  float* bnbuf = (float*)(wsb + A_BN);
  short* colF = (short*)(wsb + A_COLF);

  prep<<<2048 + 2304 + 288, 256, 0, stream>>>(x, w_om, w_dcn, bn_gamma,
                                              bn_beta, bn_mean, bn_var, xbf,
                                              Wa, Wom, bnbuf);
  om_gemm<<<512, 256, 0, stream>>>(xbf, b_om, Wom, midx, mwgt);
  im2col<<<18432, 256, 0, stream>>>(xbf, midx, mwgt, colF);
  dcn_gemm<<<512, 256, 0, stream>>>(Wa, colF, bnbuf, out);
}

// Round 11
// 111.678 us; speedup vs baseline: 1.5334x; 1.2979x over previous
//
#include <hip/hip_runtime.h>
#include <math.h>

#define B_  4
#define C1_ 256
#define C2_ 256
#define H_  64
#define W_  64
#define HW_ 4096
#define KK_ 9

// ws byte offsets (total 88,754,176 — ws >= 97,142,784 proven in R9)
#define A_WA     0u           // bf16 Wa[72][4][256][8]       1,179,648
#define A_XT     1179648u     // bf16 xT[B][HW][C1]           8,388,608  (pos-major!)
#define A_MIDX   9568256u     // int2 midx[B][9][4096]        1,179,648
#define A_MWGT   10747904u    // float4 mwgt[B][9][4096]      2,359,296
#define A_WOM    13107200u    // bf16 Wom[72][4][32][8]         147,456
#define A_BN     13254656u    // float inv[256]; bb[256]          2,048
#define A_COLF   13256704u    // bf16 colF[256][36][4096]    75,497,472

typedef short bf16x8 __attribute__((ext_vector_type(8)));
typedef float f32x4 __attribute__((ext_vector_type(4)));

__device__ __forceinline__ unsigned f2bfu(float f) {
  unsigned u = __builtin_bit_cast(unsigned, f);
  return (u + 0x7FFFu + ((u >> 16) & 1u)) >> 16;
}
__device__ __forceinline__ float bfl(unsigned short u) {
  return __builtin_bit_cast(float, (unsigned)u << 16);
}
__device__ __forceinline__ float bfe(bf16x8 v, int i) {
  return __builtin_bit_cast(float, (unsigned)(unsigned short)v[i] << 16);
}
__device__ __forceinline__ void gload_lds16(const void* g, void* l) {
  __builtin_amdgcn_global_load_lds(
      (const __attribute__((address_space(1))) unsigned*)g,
      (__attribute__((address_space(3))) unsigned*)l, 16, 0, 0);
}

// grid 512: 8 XCDs; each XCD owns 32 consecutive rows of ONE batch.
__device__ __forceinline__ void decode_bid512(int bid, int& b, int& h, int& ph) {
  const int xcd = bid & 7, slot = bid >> 3;
  b = xcd >> 1;
  h = (xcd & 1) * 32 + (slot >> 1);
  ph = slot & 1;
}

// ---------------------------------------------------------------------------
// prep: xT transpose (blocks 0..1023) + wt_perm (1024..3327) + wom_perm/BN
// (3328..3615).
// Transpose: 64c x 64pos tile through LDS; x [b][c][pos] f32 -> xT [b][pos][c]
// bf16. Reads pos-coalesced, writes 16B chunks along c.
// ---------------------------------------------------------------------------
__global__ __launch_bounds__(256) void prep(
    const float* __restrict__ x, const float* __restrict__ w_om,
    const float* __restrict__ w_dcn, const float* __restrict__ bn_gamma,
    const float* __restrict__ bn_beta, const float* __restrict__ bn_mean,
    const float* __restrict__ bn_var, unsigned short* __restrict__ xT,
    unsigned short* __restrict__ Wa, unsigned short* __restrict__ Wom,
    float* __restrict__ bnbuf) {
  const int bid = blockIdx.x;
  const int tid = threadIdx.x;
  if (bid < 1024) {
    __shared__ unsigned short T[64][68];  // +4 pad vs bank conflicts
    const int b = bid >> 8;
    const int rem = bid & 255;
    const int pos0 = (rem >> 2) * 64;
    const int c0 = (rem & 3) * 64;
    const int pl = tid & 63;
    const int ch = tid >> 6;
#pragma unroll
    for (int r = 0; r < 16; ++r) {
      const int cl = ch * 16 + r;
      const float v = x[((size_t)(b * C1_ + c0 + cl)) * HW_ + pos0 + pl];
      T[cl][pl] = (unsigned short)f2bfu(v);
    }
    __syncthreads();
    unsigned short* dst = xT + ((size_t)b * HW_ + pos0) * 256 + c0;
#pragma unroll
    for (int it = 0; it < 2; ++it) {
      const int q = it * 256 + tid;
      const int pp = q >> 3, cc = (q & 7) * 8;
      unsigned t0 = T[cc + 0][pp], t1 = T[cc + 1][pp], t2 = T[cc + 2][pp],
               t3 = T[cc + 3][pp], t4 = T[cc + 4][pp], t5 = T[cc + 5][pp],
               t6 = T[cc + 6][pp], t7 = T[cc + 7][pp];
      *(int4*)(dst + (size_t)pp * 256 + cc) =
          make_int4(t0 | (t1 << 16), t2 | (t3 << 16), t4 | (t5 << 16),
                    t6 | (t7 << 16));
    }
  } else if (bid < 1024 + 2304) {
    const unsigned e = (bid - 1024) * 256 + tid;  // < 589824
    const unsigned kt = e >> 13, r2 = e & 8191;
    const unsigned kg = r2 >> 11, r3 = r2 & 2047, o = r3 >> 3, j = r3 & 7;
    const unsigned ck = kt * 32 + kg * 8 + j;
    const unsigned k = ck >> 8, c = ck & 255;
    Wa[e] = (unsigned short)f2bfu(w_dcn[((size_t)o * C1_ + c) * 9 + k]);
  } else {
    const int wb = bid - (1024 + 2304);
    if (wb == 0) {
      const int o = tid;
      float inv = bn_gamma[o] * rsqrtf(bn_var[o] + 1e-5f);
      bnbuf[o] = inv;
      bnbuf[256 + o] = bn_beta[o] - bn_mean[o] * inv;
    }
    const unsigned e = wb * 256 + tid;  // < 73728
    const unsigned kt = e >> 10, kg = (e >> 8) & 3, o = (e >> 3) & 31, j = e & 7;
    const unsigned ck = kt * 32 + kg * 8 + j;
    const unsigned k = ck >> 8, c = ck & 255;
    const float v = (o < 27) ? w_om[((size_t)o * C1_ + c) * 9 + k] : 0.f;
    Wom[e] = (unsigned short)f2bfu(v);
  }
}

// ---------------------------------------------------------------------------
// om_gemm: om = Wom^T x im2col(xT) via MFMA + fused meta epilogue.
// Producer now: 16 consecutive channels at one pos = 2 predicated 16B loads
// from xT, already in packed-pair format (no ALU). BK=128, 18 steps.
// grid 512 (2 blocks/CU), XCD-swizzled.
// ---------------------------------------------------------------------------
__global__ __launch_bounds__(256) void om_gemm(
    const unsigned short* __restrict__ xT, const float* __restrict__ b_om,
    const unsigned short* __restrict__ Wom, int2* __restrict__ midx,
    float4* __restrict__ mwgt) {
  __shared__ short Ald[2][4096];  // [16 kg][32 o][8 j]
  __shared__ short Bld[2][4096];  // [16 kg][32 p][8 j]
  __shared__ float omld[32][33];

  int b, h, ph;
  decode_bid512(blockIdx.x, b, h, ph);
  const int tid = threadIdx.x;
  const int lane = tid & 63, wid = tid >> 6;
  const int wo = wid >> 1, wp = wid & 1;
  const int p = tid & 31;
  const int cr = tid >> 5;  // 8 groups x 16 channels

  const unsigned short* xTb = xT + (size_t)b * HW_ * 256;

  f32x4 acc = (f32x4){0.f, 0.f, 0.f, 0.f};

  auto stageA = [&](int s, int buf) {
    const char* src = (const char*)(Wom + (size_t)s * 4096);
    gload_lds16(src + tid * 16, (char*)&Ald[buf][0] + tid * 16);
    gload_lds16(src + (256 + tid) * 16, (char*)&Ald[buf][0] + (256 + tid) * 16);
  };

  // step s: k = s>>1, channel half = (s&1)*128; 16 contiguous channels
  auto produce = [&](int s, int4& uA, int4& uB) {
    const int k = s >> 1;
    const int c0 = (s & 1) * 128 + cr * 16;
    const int hh = h - 1 + k / 3;
    const int ww = ph * 32 + p - 1 + k % 3;
    const bool v = ((unsigned)hh < (unsigned)H_) && ((unsigned)ww < (unsigned)W_);
    const unsigned short* pl = xTb + (size_t)(v ? hh * W_ + ww : 0) * 256 + c0;
    uA = v ? *(const int4*)pl : make_int4(0, 0, 0, 0);
    uB = v ? *(const int4*)(pl + 8) : make_int4(0, 0, 0, 0);
  };

  const int bslot = (cr * 2) * 256 + p * 8;  // shorts; second octet +256

  auto compute = [&](int buf) {
    const int kg = lane >> 4, rr = lane & 15;
#pragma unroll
    for (int kh = 0; kh < 4; ++kh) {
      bf16x8 af = *(const bf16x8*)&Ald[buf][(kh * 4 + kg) * 256 + (wo * 16 + rr) * 8];
      bf16x8 bfr = *(const bf16x8*)&Bld[buf][(kh * 4 + kg) * 256 + (wp * 16 + rr) * 8];
      acc = __builtin_amdgcn_mfma_f32_16x16x32_bf16(af, bfr, acc, 0, 0, 0);
    }
  };

  {
    int4 uA, uB;
    produce(0, uA, uB);
    *(int4*)&Bld[0][bslot] = uA;
    *(int4*)&Bld[0][bslot + 256] = uB;
    stageA(0, 0);
  }
  __syncthreads();

  for (int s = 0; s < 18; ++s) {
    const int cur = s & 1, nxt = cur ^ 1;
    const bool pre = (s < 17);
    int4 uA, uB;
    if (pre) {
      produce(s + 1, uA, uB);  // loads in flight during compute
      stageA(s + 1, nxt);
    }
    compute(cur);
    if (pre) {
      *(int4*)&Bld[nxt][bslot] = uA;
      *(int4*)&Bld[nxt][bslot + 256] = uB;
    }
    __syncthreads();
  }

  {
    const int rr = lane & 15, rh = lane >> 4;
#pragma unroll
    for (int r = 0; r < 4; ++r) omld[wo * 16 + rh * 4 + r][wp * 16 + rr] = acc[r];
  }
  __syncthreads();

  if (tid < 32) {
    const int pc = tid;
    float a[27];
#pragma unroll
    for (int oc = 0; oc < 27; ++oc) a[oc] = omld[oc][pc] + b_om[oc];

    const int pcol = ph * 32 + pc;
#pragma unroll
    for (int k = 0; k < 9; ++k) {
      float dy = fminf(fmaxf(a[2 * k], -6.f), 6.f);
      float dx = fminf(fmaxf(a[2 * k + 1], -6.f), 6.f);
      float m = 1.f / (1.f + expf(-a[18 + k]));
      float py = (float)(h - 1 + k / 3) + dy;
      float px = (float)(pcol - 1 + k % 3) + dx;
      float y0f = floorf(py), x0f = floorf(px);
      float ly = py - y0f, lx = px - x0f;
      int y0 = (int)y0f, x0 = (int)x0f;
      int y1 = y0 + 1, x1 = x0 + 1;
      const bool vy0 = ((unsigned)y0 < (unsigned)H_);
      const bool vy1 = ((unsigned)y1 < (unsigned)H_);
      const bool vx0 = ((unsigned)x0 < (unsigned)W_);
      const bool vx1 = ((unsigned)x1 < (unsigned)W_);
      int y0c = min(max(y0, 0), H_ - 1), y1c = min(max(y1, 0), H_ - 1);
      int x0c = min(max(x0, 0), W_ - 1), x1c = min(max(x1, 0), W_ - 1);
      const int xbc = min(max(x0, 0), W_ - 2);
      float wx0 = 0.f, wx1 = 0.f;
      if (vx0) { if (x0c == xbc) wx0 += 1.f - lx; else wx1 += 1.f - lx; }
      if (vx1) { if (x1c == xbc) wx0 += lx; else wx1 += lx; }
      const float wy0 = vy0 ? (1.f - ly) : 0.f;
      const float wy1 = vy1 ? ly : 0.f;
      const size_t e = ((size_t)b * KK_ + k) * HW_ + h * W_ + pcol;
      midx[e] = make_int2(y0c * W_ + xbc, y1c * W_ + xbc);
      mwgt[e] = make_float4(m * wy0 * wx0, m * wy0 * wx1, m * wy1 * wx0,
                            m * wy1 * wx1);
    }
  }
}

// ---------------------------------------------------------------------------
// im2col: barrier-free gather -> colF in MFMA fragment order.
// With pos-major xT, each thread's 8 channels x 4 taps = FOUR 16B vector
// loads (was 32 scalar loads). Same grid/output mapping as R10.
// ---------------------------------------------------------------------------
__global__ __launch_bounds__(256) void im2col(
    const unsigned short* __restrict__ xT, const int2* __restrict__ midx,
    const float4* __restrict__ mwgt, short* __restrict__ colF) {
  const int bid = blockIdx.x;
  const int xcd = bid & 7;
  const int b = xcd >> 1;
  const unsigned rest = bid >> 3;          // 0..2303
  const unsigned h_lo = rest / 72u, sub = rest % 72u;
  const int h = (xcd & 1) * 32 + (int)h_lo;
  const int tid = threadIdx.x;
  const int p = tid & 63;
  const int oi = (int)sub * 4 + (tid >> 6);  // 0..287
  const int s = oi >> 3, kh = (oi >> 2) & 1, kg = oi & 3;
  const int ckb = s * 64 + kh * 32 + kg * 8;
  const int k = ckb >> 8, c0 = ckb & 255;

  const size_t em = ((size_t)b * KK_ + k) * HW_ + h * W_ + p;
  const int2 mi = midx[em];
  const float4 mw = mwgt[em];

  const unsigned short* base = xT + (size_t)b * HW_ * 256 + c0;
  const bf16x8 A = *(const bf16x8*)(base + (size_t)mi.x * 256);
  const bf16x8 Bv = *(const bf16x8*)(base + (size_t)(mi.x + 1) * 256);
  const bf16x8 Cv = *(const bf16x8*)(base + (size_t)mi.y * 256);
  const bf16x8 Dv = *(const bf16x8*)(base + (size_t)(mi.y + 1) * 256);

  unsigned bf[8];
#pragma unroll
  for (int j = 0; j < 8; ++j) {
    float v = mw.x * bfe(A, j) + mw.y * bfe(Bv, j) + mw.z * bfe(Cv, j) +
              mw.w * bfe(Dv, j);
    bf[j] = f2bfu(v);
  }
  short* dst = colF + ((size_t)(b * 64 + h) * 36 + s) * 4096 +
               ((kh * 4 + kg) * 64 + p) * 8;
  *(int4*)dst = make_int4(bf[0] | (bf[1] << 16), bf[2] | (bf[3] << 16),
                          bf[4] | (bf[5] << 16), bf[6] | (bf[7] << 16));
}

// ---------------------------------------------------------------------------
// dcn_gemm: unchanged from R10. out = Wa^T x colF, fused BN+SiLU.
// Block O=128 x P=64, 256 thr = 4 waves, BK=64, 36 steps, 48 KB LDS,
// grid 512 = 2 blocks/CU.
// ---------------------------------------------------------------------------
__global__ __launch_bounds__(256) void dcn_gemm(
    const unsigned short* __restrict__ Wa, const short* __restrict__ colF,
    const float* __restrict__ bnbuf, float* __restrict__ out) {
  __shared__ short Ald[2][8192];  // [2 kt'][4 kg][128 o][8 j]  16 KB/buf
  __shared__ short Bld[2][4096];  // [2 kh][4 kg][64 p][8 j]     8 KB/buf

  const int bid = blockIdx.x;
  const int xcd = bid & 7;
  const int b = xcd >> 1;
  const int rest = bid >> 3;  // 0..63
  const int oh = rest & 1;
  const int h = (xcd & 1) * 32 + (rest >> 1);
  const int tid = threadIdx.x;
  const int lane = tid & 63, wid = tid >> 6;
  const int wo = wid >> 1, wp = wid & 1;

  const short* colFb = colF + (size_t)(b * 64 + h) * 36 * 4096;

  f32x4 acc[4][2];
#pragma unroll
  for (int i = 0; i < 4; ++i)
#pragma unroll
    for (int j = 0; j < 2; ++j) acc[i][j] = (f32x4){0.f, 0.f, 0.f, 0.f};

  auto stage = [&](int s, int buf) {
#pragma unroll
    for (int r = 0; r < 4; ++r) {
      const int c = r * 256 + tid;           // 0..1023
      const int slice = c >> 7;              // kt'*4+kg
      const int wtn = c & 127;               // o within 128
      const size_t srcs = (size_t)(2 * s + (slice >> 2)) * 8192 +
                          (size_t)(slice & 3) * 2048 + (size_t)oh * 1024 +
                          (size_t)wtn * 8;
      gload_lds16((const char*)(Wa + srcs), (char*)&Ald[buf][0] + c * 16);
    }
#pragma unroll
    for (int r = 0; r < 2; ++r) {
      const int c = r * 256 + tid;
      gload_lds16((const char*)(colFb + (size_t)s * 4096) + c * 16,
                  (char*)&Bld[buf][0] + c * 16);
    }
  };

  auto compute = [&](int buf) {
    const int kg = lane >> 4, rr = lane & 15;
    bf16x8 af[4][2], bfr[2][2];
#pragma unroll
    for (int kh = 0; kh < 2; ++kh) {
#pragma unroll
      for (int fm = 0; fm < 4; ++fm)
        af[fm][kh] = *(const bf16x8*)&Ald[buf][kh * 4096 + kg * 1024 +
                                              (wo * 64 + fm * 16 + rr) * 8];
#pragma unroll
      for (int fn = 0; fn < 2; ++fn)
        bfr[fn][kh] = *(const bf16x8*)&Bld[buf][kh * 2048 + kg * 512 +
                                               (wp * 32 + fn * 16 + rr) * 8];
    }
#pragma unroll
    for (int kh = 0; kh < 2; ++kh)
#pragma unroll
      for (int fm = 0; fm < 4; ++fm)
#pragma unroll
        for (int fn = 0; fn < 2; ++fn)
          acc[fm][fn] = __builtin_amdgcn_mfma_f32_16x16x32_bf16(
              af[fm][kh], bfr[fn][kh], acc[fm][fn], 0, 0, 0);
  };

  stage(0, 0);
  __syncthreads();
  for (int s = 0; s < 36; ++s) {
    const int cur = s & 1;
    if (s < 35) stage(s + 1, cur ^ 1);
    compute(cur);
    __syncthreads();
  }

  const float* bninv = bnbuf;
  const float* bnbb = bnbuf + 256;
  const int rr = lane & 15, rh = lane >> 4;
#pragma unroll
  for (int fm = 0; fm < 4; ++fm) {
#pragma unroll
    for (int r = 0; r < 4; ++r) {
      const int o = oh * 128 + wo * 64 + fm * 16 + rh * 4 + r;
      const float inv = bninv[o], bb = bnbb[o];
#pragma unroll
      for (int fn = 0; fn < 2; ++fn) {
        float t = acc[fm][fn][r] * inv + bb;
        float sv = t / (1.f + expf(-t));
        out[(size_t)(b * C2_ + o) * HW_ + h * W_ + wp * 32 + fn * 16 + rr] = sv;
      }
    }
  }
}

// ---------------------------------------------------------------------------
extern "C" void kernel_launch(void* const* d_in, const int* in_sizes, int n_in,
                              void* d_out, int out_size, void* d_ws,
                              size_t ws_size, hipStream_t stream) {
  const float* x = (const float*)d_in[0];
  const float* w_om = (const float*)d_in[1];
  const float* b_om = (const float*)d_in[2];
  const float* w_dcn = (const float*)d_in[3];
  const float* bn_gamma = (const float*)d_in[4];
  const float* bn_beta = (const float*)d_in[5];
  const float* bn_mean = (const float*)d_in[6];
  const float* bn_var = (const float*)d_in[7];
  float* out = (float*)d_out;
  char* wsb = (char*)d_ws;

  unsigned short* Wa = (unsigned short*)(wsb + A_WA);
  unsigned short* xT = (unsigned short*)(wsb + A_XT);
  int2* midx = (int2*)(wsb + A_MIDX);
  float4* mwgt = (float4*)(wsb + A_MWGT);
  unsigned short* Wom = (unsigned short*)(wsb + A_WOM);
  float* bnbuf = (float*)(wsb + A_BN);
  short* colF = (short*)(wsb + A_COLF);

  prep<<<1024 + 2304 + 288, 256, 0, stream>>>(x, w_om, w_dcn, bn_gamma,
                                              bn_beta, bn_mean, bn_var, xT,
                                              Wa, Wom, bnbuf);
  om_gemm<<<512, 256, 0, stream>>>(xT, b_om, Wom, midx, mwgt);
  im2col<<<18432, 256, 0, stream>>>(xT, midx, mwgt, colF);
  dcn_gemm<<<512, 256, 0, stream>>>(Wa, colF, bnbuf, out);
}

// Round 12
// 106.496 us; speedup vs baseline: 1.6080x; 1.0487x over previous
//
#include <hip/hip_runtime.h>
#include <math.h>

#define B_  4
#define C1_ 256
#define C2_ 256
#define H_  64
#define W_  64
#define HW_ 4096
#define KK_ 9

// ws byte offsets (total 88,754,176 — ws >= 97,142,784 proven in R9)
#define A_WA     0u           // bf16 Wa[72][4][256][8]       1,179,648
#define A_XT     1179648u     // bf16 xT[B][HW][C1]           8,388,608  (pos-major)
#define A_MIDX   9568256u     // int2 midx[B][9][4096]        1,179,648
#define A_MWGT   10747904u    // float4 mwgt[B][9][4096]      2,359,296
#define A_WOM    13107200u    // bf16 Wom[72][4][32][8]         147,456
#define A_BN     13254656u    // float inv[256]; bb[256]          2,048
#define A_COLF   13256704u    // bf16 colF[256][36][4096]    75,497,472

typedef short bf16x8 __attribute__((ext_vector_type(8)));
typedef float f32x4 __attribute__((ext_vector_type(4)));

__device__ __forceinline__ unsigned f2bfu(float f) {
  unsigned u = __builtin_bit_cast(unsigned, f);
  return (u + 0x7FFFu + ((u >> 16) & 1u)) >> 16;
}
__device__ __forceinline__ float bfl(unsigned short u) {
  return __builtin_bit_cast(float, (unsigned)u << 16);
}
__device__ __forceinline__ float bfe(bf16x8 v, int i) {
  return __builtin_bit_cast(float, (unsigned)(unsigned short)v[i] << 16);
}
__device__ __forceinline__ void gload_lds16(const void* g, void* l) {
  __builtin_amdgcn_global_load_lds(
      (const __attribute__((address_space(1))) unsigned*)g,
      (__attribute__((address_space(3))) unsigned*)l, 16, 0, 0);
}

// grid 512: 8 XCDs; each XCD owns 32 consecutive rows of ONE batch.
__device__ __forceinline__ void decode_bid512(int bid, int& b, int& h, int& ph) {
  const int xcd = bid & 7, slot = bid >> 3;
  b = xcd >> 1;
  h = (xcd & 1) * 32 + (slot >> 1);
  ph = slot & 1;
}

// ---------------------------------------------------------------------------
// prep: xT transpose (0..1023) + wt_perm (1024..3327) + wom_perm/BN (3328..).
// ---------------------------------------------------------------------------
__global__ __launch_bounds__(256) void prep(
    const float* __restrict__ x, const float* __restrict__ w_om,
    const float* __restrict__ w_dcn, const float* __restrict__ bn_gamma,
    const float* __restrict__ bn_beta, const float* __restrict__ bn_mean,
    const float* __restrict__ bn_var, unsigned short* __restrict__ xT,
    unsigned short* __restrict__ Wa, unsigned short* __restrict__ Wom,
    float* __restrict__ bnbuf) {
  const int bid = blockIdx.x;
  const int tid = threadIdx.x;
  if (bid < 1024) {
    __shared__ unsigned short T[64][68];
    const int b = bid >> 8;
    const int rem = bid & 255;
    const int pos0 = (rem >> 2) * 64;
    const int c0 = (rem & 3) * 64;
    const int pl = tid & 63;
    const int ch = tid >> 6;
#pragma unroll
    for (int r = 0; r < 16; ++r) {
      const int cl = ch * 16 + r;
      const float v = x[((size_t)(b * C1_ + c0 + cl)) * HW_ + pos0 + pl];
      T[cl][pl] = (unsigned short)f2bfu(v);
    }
    __syncthreads();
    unsigned short* dst = xT + ((size_t)b * HW_ + pos0) * 256 + c0;
#pragma unroll
    for (int it = 0; it < 2; ++it) {
      const int q = it * 256 + tid;
      const int pp = q >> 3, cc = (q & 7) * 8;
      unsigned t0 = T[cc + 0][pp], t1 = T[cc + 1][pp], t2 = T[cc + 2][pp],
               t3 = T[cc + 3][pp], t4 = T[cc + 4][pp], t5 = T[cc + 5][pp],
               t6 = T[cc + 6][pp], t7 = T[cc + 7][pp];
      *(int4*)(dst + (size_t)pp * 256 + cc) =
          make_int4(t0 | (t1 << 16), t2 | (t3 << 16), t4 | (t5 << 16),
                    t6 | (t7 << 16));
    }
  } else if (bid < 1024 + 2304) {
    const unsigned e = (bid - 1024) * 256 + tid;  // < 589824
    const unsigned kt = e >> 13, r2 = e & 8191;
    const unsigned kg = r2 >> 11, r3 = r2 & 2047, o = r3 >> 3, j = r3 & 7;
    const unsigned ck = kt * 32 + kg * 8 + j;
    const unsigned k = ck >> 8, c = ck & 255;
    Wa[e] = (unsigned short)f2bfu(w_dcn[((size_t)o * C1_ + c) * 9 + k]);
  } else {
    const int wb = bid - (1024 + 2304);
    if (wb == 0) {
      const int o = tid;
      float inv = bn_gamma[o] * rsqrtf(bn_var[o] + 1e-5f);
      bnbuf[o] = inv;
      bnbuf[256 + o] = bn_beta[o] - bn_mean[o] * inv;
    }
    const unsigned e = wb * 256 + tid;  // < 73728
    const unsigned kt = e >> 10, kg = (e >> 8) & 3, o = (e >> 3) & 31, j = e & 7;
    const unsigned ck = kt * 32 + kg * 8 + j;
    const unsigned k = ck >> 8, c = ck & 255;
    const float v = (o < 27) ? w_om[((size_t)o * C1_ + c) * 9 + k] : 0.f;
    Wom[e] = (unsigned short)f2bfu(v);
  }
}

// ---------------------------------------------------------------------------
// om_gemm: unchanged from R11.
// ---------------------------------------------------------------------------
__global__ __launch_bounds__(256) void om_gemm(
    const unsigned short* __restrict__ xT, const float* __restrict__ b_om,
    const unsigned short* __restrict__ Wom, int2* __restrict__ midx,
    float4* __restrict__ mwgt) {
  __shared__ short Ald[2][4096];
  __shared__ short Bld[2][4096];
  __shared__ float omld[32][33];

  int b, h, ph;
  decode_bid512(blockIdx.x, b, h, ph);
  const int tid = threadIdx.x;
  const int lane = tid & 63, wid = tid >> 6;
  const int wo = wid >> 1, wp = wid & 1;
  const int p = tid & 31;
  const int cr = tid >> 5;

  const unsigned short* xTb = xT + (size_t)b * HW_ * 256;

  f32x4 acc = (f32x4){0.f, 0.f, 0.f, 0.f};

  auto stageA = [&](int s, int buf) {
    const char* src = (const char*)(Wom + (size_t)s * 4096);
    gload_lds16(src + tid * 16, (char*)&Ald[buf][0] + tid * 16);
    gload_lds16(src + (256 + tid) * 16, (char*)&Ald[buf][0] + (256 + tid) * 16);
  };

  auto produce = [&](int s, int4& uA, int4& uB) {
    const int k = s >> 1;
    const int c0 = (s & 1) * 128 + cr * 16;
    const int hh = h - 1 + k / 3;
    const int ww = ph * 32 + p - 1 + k % 3;
    const bool v = ((unsigned)hh < (unsigned)H_) && ((unsigned)ww < (unsigned)W_);
    const unsigned short* pl = xTb + (size_t)(v ? hh * W_ + ww : 0) * 256 + c0;
    uA = v ? *(const int4*)pl : make_int4(0, 0, 0, 0);
    uB = v ? *(const int4*)(pl + 8) : make_int4(0, 0, 0, 0);
  };

  const int bslot = (cr * 2) * 256 + p * 8;

  auto compute = [&](int buf) {
    const int kg = lane >> 4, rr = lane & 15;
#pragma unroll
    for (int kh = 0; kh < 4; ++kh) {
      bf16x8 af = *(const bf16x8*)&Ald[buf][(kh * 4 + kg) * 256 + (wo * 16 + rr) * 8];
      bf16x8 bfr = *(const bf16x8*)&Bld[buf][(kh * 4 + kg) * 256 + (wp * 16 + rr) * 8];
      acc = __builtin_amdgcn_mfma_f32_16x16x32_bf16(af, bfr, acc, 0, 0, 0);
    }
  };

  {
    int4 uA, uB;
    produce(0, uA, uB);
    *(int4*)&Bld[0][bslot] = uA;
    *(int4*)&Bld[0][bslot + 256] = uB;
    stageA(0, 0);
  }
  __syncthreads();

  for (int s = 0; s < 18; ++s) {
    const int cur = s & 1, nxt = cur ^ 1;
    const bool pre = (s < 17);
    int4 uA, uB;
    if (pre) {
      produce(s + 1, uA, uB);
      stageA(s + 1, nxt);
    }
    compute(cur);
    if (pre) {
      *(int4*)&Bld[nxt][bslot] = uA;
      *(int4*)&Bld[nxt][bslot + 256] = uB;
    }
    __syncthreads();
  }

  {
    const int rr = lane & 15, rh = lane >> 4;
#pragma unroll
    for (int r = 0; r < 4; ++r) omld[wo * 16 + rh * 4 + r][wp * 16 + rr] = acc[r];
  }
  __syncthreads();

  if (tid < 32) {
    const int pc = tid;
    float a[27];
#pragma unroll
    for (int oc = 0; oc < 27; ++oc) a[oc] = omld[oc][pc] + b_om[oc];

    const int pcol = ph * 32 + pc;
#pragma unroll
    for (int k = 0; k < 9; ++k) {
      float dy = fminf(fmaxf(a[2 * k], -6.f), 6.f);
      float dx = fminf(fmaxf(a[2 * k + 1], -6.f), 6.f);
      float m = 1.f / (1.f + expf(-a[18 + k]));
      float py = (float)(h - 1 + k / 3) + dy;
      float px = (float)(pcol - 1 + k % 3) + dx;
      float y0f = floorf(py), x0f = floorf(px);
      float ly = py - y0f, lx = px - x0f;
      int y0 = (int)y0f, x0 = (int)x0f;
      int y1 = y0 + 1, x1 = x0 + 1;
      const bool vy0 = ((unsigned)y0 < (unsigned)H_);
      const bool vy1 = ((unsigned)y1 < (unsigned)H_);
      const bool vx0 = ((unsigned)x0 < (unsigned)W_);
      const bool vx1 = ((unsigned)x1 < (unsigned)W_);
      int y0c = min(max(y0, 0), H_ - 1), y1c = min(max(y1, 0), H_ - 1);
      int x0c = min(max(x0, 0), W_ - 1), x1c = min(max(x1, 0), W_ - 1);
      const int xbc = min(max(x0, 0), W_ - 2);
      float wx0 = 0.f, wx1 = 0.f;
      if (vx0) { if (x0c == xbc) wx0 += 1.f - lx; else wx1 += 1.f - lx; }
      if (vx1) { if (x1c == xbc) wx0 += lx; else wx1 += lx; }
      const float wy0 = vy0 ? (1.f - ly) : 0.f;
      const float wy1 = vy1 ? ly : 0.f;
      const size_t e = ((size_t)b * KK_ + k) * HW_ + h * W_ + pcol;
      midx[e] = make_int2(y0c * W_ + xbc, y1c * W_ + xbc);
      mwgt[e] = make_float4(m * wy0 * wx0, m * wy0 * wx1, m * wy1 * wx0,
                            m * wy1 * wx1);
    }
  }
}

// ---------------------------------------------------------------------------
// im2col: unchanged from R11 (vectorized xT gathers).
// ---------------------------------------------------------------------------
__global__ __launch_bounds__(256) void im2col(
    const unsigned short* __restrict__ xT, const int2* __restrict__ midx,
    const float4* __restrict__ mwgt, short* __restrict__ colF) {
  const int bid = blockIdx.x;
  const int xcd = bid & 7;
  const int b = xcd >> 1;
  const unsigned rest = bid >> 3;
  const unsigned h_lo = rest / 72u, sub = rest % 72u;
  const int h = (xcd & 1) * 32 + (int)h_lo;
  const int tid = threadIdx.x;
  const int p = tid & 63;
  const int oi = (int)sub * 4 + (tid >> 6);
  const int s = oi >> 3, kh = (oi >> 2) & 1, kg = oi & 3;
  const int ckb = s * 64 + kh * 32 + kg * 8;
  const int k = ckb >> 8, c0 = ckb & 255;

  const size_t em = ((size_t)b * KK_ + k) * HW_ + h * W_ + p;
  const int2 mi = midx[em];
  const float4 mw = mwgt[em];

  const unsigned short* base = xT + (size_t)b * HW_ * 256 + c0;
  const bf16x8 A = *(const bf16x8*)(base + (size_t)mi.x * 256);
  const bf16x8 Bv = *(const bf16x8*)(base + (size_t)(mi.x + 1) * 256);
  const bf16x8 Cv = *(const bf16x8*)(base + (size_t)mi.y * 256);
  const bf16x8 Dv = *(const bf16x8*)(base + (size_t)(mi.y + 1) * 256);

  unsigned bf[8];
#pragma unroll
  for (int j = 0; j < 8; ++j) {
    float v = mw.x * bfe(A, j) + mw.y * bfe(Bv, j) + mw.z * bfe(Cv, j) +
              mw.w * bfe(Dv, j);
    bf[j] = f2bfu(v);
  }
  short* dst = colF + ((size_t)(b * 64 + h) * 36 + s) * 4096 +
               ((kh * 4 + kg) * 64 + p) * 8;
  *(int4*)dst = make_int4(bf[0] | (bf[1] << 16), bf[2] | (bf[3] << 16),
                          bf[4] | (bf[5] << 16), bf[6] | (bf[7] << 16));
}

// ---------------------------------------------------------------------------
// dcn_gemm: counted-vmcnt, TRIPLE-buffered pure-gload_lds pipeline.
// Per step s: issue 6 stage-loads for s+2 -> compute s -> vmcnt(6) (completes
// stage(s+1), leaves stage(s+2) in flight ACROSS the barrier) -> s_barrier.
// No register gather arrays anywhere (the R8 scratch hazard is absent).
// Block O=128 x P=64, 256 thr, BK=64, 36 steps, LDS 72 KB -> 2 blocks/CU.
// ---------------------------------------------------------------------------
__global__ __launch_bounds__(256) void dcn_gemm(
    const unsigned short* __restrict__ Wa, const short* __restrict__ colF,
    const float* __restrict__ bnbuf, float* __restrict__ out) {
  __shared__ short Ald[3][8192];  // [2 kt'][4 kg][128 o][8 j]  16 KB/buf
  __shared__ short Bld[3][4096];  // [2 kh][4 kg][64 p][8 j]     8 KB/buf

  const int bid = blockIdx.x;
  const int xcd = bid & 7;
  const int b = xcd >> 1;
  const int rest = bid >> 3;  // 0..63
  const int oh = rest & 1;
  const int h = (xcd & 1) * 32 + (rest >> 1);
  const int tid = threadIdx.x;
  const int lane = tid & 63, wid = tid >> 6;
  const int wo = wid >> 1, wp = wid & 1;

  const short* colFb = colF + (size_t)(b * 64 + h) * 36 * 4096;

  f32x4 acc[4][2];
#pragma unroll
  for (int i = 0; i < 4; ++i)
#pragma unroll
    for (int j = 0; j < 2; ++j) acc[i][j] = (f32x4){0.f, 0.f, 0.f, 0.f};

  // exactly 6 gload_lds per call (4 A + 2 B) — vmcnt bookkeeping depends on it
  auto stage = [&](int s, int buf) {
#pragma unroll
    for (int r = 0; r < 4; ++r) {
      const int c = r * 256 + tid;           // 0..1023
      const int slice = c >> 7;              // kt'*4+kg
      const int wtn = c & 127;               // o within 128
      const size_t srcs = (size_t)(2 * s + (slice >> 2)) * 8192 +
                          (size_t)(slice & 3) * 2048 + (size_t)oh * 1024 +
                          (size_t)wtn * 8;
      gload_lds16((const char*)(Wa + srcs), (char*)&Ald[buf][0] + c * 16);
    }
#pragma unroll
    for (int r = 0; r < 2; ++r) {
      const int c = r * 256 + tid;
      gload_lds16((const char*)(colFb + (size_t)s * 4096) + c * 16,
                  (char*)&Bld[buf][0] + c * 16);
    }
  };

  auto compute = [&](int buf) {
    const int kg = lane >> 4, rr = lane & 15;
    bf16x8 af[4][2], bfr[2][2];
#pragma unroll
    for (int kh = 0; kh < 2; ++kh) {
#pragma unroll
      for (int fm = 0; fm < 4; ++fm)
        af[fm][kh] = *(const bf16x8*)&Ald[buf][kh * 4096 + kg * 1024 +
                                              (wo * 64 + fm * 16 + rr) * 8];
#pragma unroll
      for (int fn = 0; fn < 2; ++fn)
        bfr[fn][kh] = *(const bf16x8*)&Bld[buf][kh * 2048 + kg * 512 +
                                               (wp * 32 + fn * 16 + rr) * 8];
    }
#pragma unroll
    for (int kh = 0; kh < 2; ++kh)
#pragma unroll
      for (int fm = 0; fm < 4; ++fm)
#pragma unroll
        for (int fn = 0; fn < 2; ++fn)
          acc[fm][fn] = __builtin_amdgcn_mfma_f32_16x16x32_bf16(
              af[fm][kh], bfr[fn][kh], acc[fm][fn], 0, 0, 0);
  };

  // prologue: stage 0,1; complete stage(0) (vmcnt(6)), stage(1) stays in flight
  stage(0, 0);
  stage(1, 1);
  asm volatile("s_waitcnt vmcnt(6) lgkmcnt(0)" ::: "memory");
  __builtin_amdgcn_s_barrier();
  __builtin_amdgcn_sched_barrier(0);

  // steady state invariant at each barrier: newest 6 loads (stage s+2) in
  // flight; everything older complete.
#define DCN_STEP(S, BUF)                                            \
  {                                                                 \
    const int s_ = (S);                                             \
    const bool pre_ = (s_ + 2 < 36);                                \
    if (pre_) stage(s_ + 2, ((BUF) + 2) % 3);                       \
    compute(BUF);                                                   \
    if (pre_) {                                                     \
      asm volatile("s_waitcnt vmcnt(6) lgkmcnt(0)" ::: "memory");   \
      __builtin_amdgcn_s_barrier();                                 \
      __builtin_amdgcn_sched_barrier(0);                            \
    } else if (s_ + 1 < 36) {                                       \
      asm volatile("s_waitcnt vmcnt(0) lgkmcnt(0)" ::: "memory");   \
      __builtin_amdgcn_s_barrier();                                 \
      __builtin_amdgcn_sched_barrier(0);                            \
    }                                                               \
  }

  for (int sb = 0; sb < 36; sb += 3) {
    DCN_STEP(sb + 0, 0);
    DCN_STEP(sb + 1, 1);
    DCN_STEP(sb + 2, 2);
  }
#undef DCN_STEP

  const float* bninv = bnbuf;
  const float* bnbb = bnbuf + 256;
  const int rr = lane & 15, rh = lane >> 4;
#pragma unroll
  for (int fm = 0; fm < 4; ++fm) {
#pragma unroll
    for (int r = 0; r < 4; ++r) {
      const int o = oh * 128 + wo * 64 + fm * 16 + rh * 4 + r;
      const float inv = bninv[o], bb = bnbb[o];
#pragma unroll
      for (int fn = 0; fn < 2; ++fn) {
        float t = acc[fm][fn][r] * inv + bb;
        float sv = t / (1.f + expf(-t));
        out[(size_t)(b * C2_ + o) * HW_ + h * W_ + wp * 32 + fn * 16 + rr] = sv;
      }
    }
  }
}

// ---------------------------------------------------------------------------
extern "C" void kernel_launch(void* const* d_in, const int* in_sizes, int n_in,
                              void* d_out, int out_size, void* d_ws,
                              size_t ws_size, hipStream_t stream) {
  const float* x = (const float*)d_in[0];
  const float* w_om = (const float*)d_in[1];
  const float* b_om = (const float*)d_in[2];
  const float* w_dcn = (const float*)d_in[3];
  const float* bn_gamma = (const float*)d_in[4];
  const float* bn_beta = (const float*)d_in[5];
  const float* bn_mean = (const float*)d_in[6];
  const float* bn_var = (const float*)d_in[7];
  float* out = (float*)d_out;
  char* wsb = (char*)d_ws;

  unsigned short* Wa = (unsigned short*)(wsb + A_WA);
  unsigned short* xT = (unsigned short*)(wsb + A_XT);
  int2* midx = (int2*)(wsb + A_MIDX);
  float4* mwgt = (float4*)(wsb + A_MWGT);
  unsigned short* Wom = (unsigned short*)(wsb + A_WOM);
  float* bnbuf = (float*)(wsb + A_BN);
  short* colF = (short*)(wsb + A_COLF);

  prep<<<1024 + 2304 + 288, 256, 0, stream>>>(x, w_om, w_dcn, bn_gamma,
                                              bn_beta, bn_mean, bn_var, xT,
                                              Wa, Wom, bnbuf);
  om_gemm<<<512, 256, 0, stream>>>(xT, b_om, Wom, midx, mwgt);
  im2col<<<18432, 256, 0, stream>>>(xT, midx, mwgt, colF);
  dcn_gemm<<<512, 256, 0, stream>>>(Wa, colF, bnbuf, out);
}